// Round 4
// baseline (395.236 us; speedup 1.0000x reference)
//
#include <hip/hip_runtime.h>
#include <cstdint>
#include <cstddef>

typedef unsigned short u16;
typedef __bf16 bf16x8 __attribute__((ext_vector_type(8)));
typedef __bf16 bf16x2 __attribute__((ext_vector_type(2)));
typedef float f32x4 __attribute__((ext_vector_type(4)));
typedef uint32_t u32x4 __attribute__((ext_vector_type(4)));

__device__ inline u16 f2bf(float f) {
  uint32_t u = __builtin_bit_cast(uint32_t, f);
  u += 0x7fffu + ((u >> 16) & 1u);
  return (u16)(u >> 16);
}
__device__ inline float bf2f(u16 u) {
  return __builtin_bit_cast(float, (uint32_t)u << 16);
}

#if defined(__has_builtin)
#if __has_builtin(__builtin_amdgcn_cvt_pk_bf16_f32)
#define HAVE_PK_BF16 1
#endif
#if __has_builtin(__builtin_amdgcn_exp2f)
#define EXP2(x) __builtin_amdgcn_exp2f(x)
#endif
#endif
#ifndef EXP2
#define EXP2(x) exp2f(x)
#endif

__device__ inline uint32_t pk2bf(float a, float b) {
#ifdef HAVE_PK_BF16
  bf16x2 v = __builtin_amdgcn_cvt_pk_bf16_f32(a, b);
  return __builtin_bit_cast(uint32_t, v);
#else
  return (uint32_t)f2bf(a) | ((uint32_t)f2bf(b) << 16);
#endif
}

__device__ inline f32x4 mfma16(bf16x8 a, bf16x8 b, f32x4 c) {
  return __builtin_amdgcn_mfma_f32_16x16x32_bf16(a, b, c, 0, 0, 0);
}

__device__ inline void gl_lds16(const u16* g, u16* l) {
  __builtin_amdgcn_global_load_lds(
      (const __attribute__((address_space(1))) uint32_t*)g,
      (__attribute__((address_space(3))) uint32_t*)l, 16, 0, 0);
}

// ---------------- all input conversions in one launch ----------------
__device__ void tcvt_dev(const float* __restrict__ in, u16* __restrict__ out,
                         int R, int C, int bx, int by, float (*t)[33], int tid) {
  int cb = bx * 32, rb = by * 32;
  int x = tid & 31, y = tid >> 5;
#pragma unroll
  for (int k = 0; k < 4; ++k)
    t[y + k * 8][x] = in[(size_t)(rb + y + k * 8) * C + cb + x];
  __syncthreads();
#pragma unroll
  for (int k = 0; k < 4; ++k)
    out[(size_t)(cb + y + k * 8) * R + rb + x] = f2bf(t[x][y + k * 8]);
}

__global__ __launch_bounds__(256) void k_prep(
    const float* __restrict__ x, const float* __restrict__ Wq,
    const float* __restrict__ Wkvd, const float* __restrict__ Wkvu,
    const float* __restrict__ Wo, u16* __restrict__ xbf,
    u16* __restrict__ WqkdT, u16* __restrict__ WkvuT, u16* __restrict__ WoT) {
  __shared__ float t[32][33];
  int bid = blockIdx.x, tid = threadIdx.x;
  if (bid < 8192) {
    int i = bid * 256 + tid;
    const float4 v = ((const float4*)x)[i];
    ushort4 o;
    o.x = f2bf(v.x); o.y = f2bf(v.y); o.z = f2bf(v.z); o.w = f2bf(v.w);
    ((ushort4*)xbf)[i] = o;
  } else if (bid < 12288) {
    int q = bid - 8192;
    tcvt_dev(Wq, WqkdT, 2048, 2048, q & 63, q >> 6, t, tid);
  } else if (bid < 12800) {
    int q = bid - 12288;
    tcvt_dev(Wkvd, WqkdT + 2048 * 2048, 2048, 256, q & 7, q >> 3, t, tid);
  } else if (bid < 13824) {
    int q = bid - 12800;
    tcvt_dev(Wkvu, WkvuT, 256, 4096, q & 127, q >> 7, t, tid);
  } else {
    int q = bid - 13824;
    tcvt_dev(Wo, WoT, 2048, 2048, q & 63, q >> 6, t, tid);
  }
}

// ---------------- RMSNorm rows of 256 bf16 (scale-invariant) -> bf16 ----------
__global__ __launch_bounds__(256) void k_rmsn(const u16* __restrict__ qc,
                                              const float* __restrict__ w,
                                              u16* __restrict__ out) {
  int row = blockIdx.x * 4 + (threadIdx.x >> 6);
  int lane = threadIdx.x & 63;
  const ushort4 u = *(const ushort4*)(qc + (size_t)row * 2304 + 2048 + lane * 4);
  float4 v;
  v.x = bf2f(u.x); v.y = bf2f(u.y); v.z = bf2f(u.z); v.w = bf2f(u.w);
  float ss = v.x * v.x + v.y * v.y + v.z * v.z + v.w * v.w;
#pragma unroll
  for (int off = 1; off < 64; off <<= 1) ss += __shfl_xor(ss, off);
  float r = rsqrtf(ss * (1.f / 256.f) + 1e-6f);
  const float4 wv = ((const float4*)w)[lane];
  ushort4 o;
  o.x = f2bf(v.x * r * wv.x);
  o.y = f2bf(v.y * r * wv.y);
  o.z = f2bf(v.z * r * wv.z);
  o.w = f2bf(v.w * r * wv.w);
  *(ushort4*)(out + (size_t)row * 256 + lane * 4) = o;
}

// ---------------- GEMM: A[M,K] @ BT[N,K] -> C[M,N] ----------------
// MODE 0: fp32 out. MODE 1: bf16 out, scaled. MODE 2: kv split (K->C, V->C2^T).
template <int BK, int MODE>
__global__ __launch_bounds__(256) void k_gemm(const u16* __restrict__ A,
                                              const u16* __restrict__ BT,
                                              void* __restrict__ C,
                                              u16* __restrict__ C2, int K,
                                              int ldc, float scale) {
  __shared__ __align__(16) u16 As[128 * BK];
  __shared__ __align__(16) u16 Bs[128 * BK];
  const int tid = threadIdx.x, wave = tid >> 6, lane = tid & 63;
  const int lanem = lane & 15, quad = lane >> 4;
  const int m0 = blockIdx.x * 128, n0 = blockIdx.y * 128;
  const int wr = wave >> 1, wc = wave & 1;
  f32x4 acc[4][4] = {};
  for (int k0 = 0; k0 < K; k0 += BK) {
    __syncthreads();
    if constexpr (BK == 32) {
      const int srow = lane >> 2, scol = (lane & 3) * 8;
#pragma unroll
      for (int c = 0; c < 2; ++c) {
        int p = wave * 2 + c;
        gl_lds16(A + (size_t)(m0 + p * 16 + srow) * K + k0 + scol, &As[p * 512]);
        gl_lds16(BT + (size_t)(n0 + p * 16 + srow) * K + k0 + scol, &Bs[p * 512]);
      }
    } else {
      const int srow = lane >> 3;
      const int scol = ((lane & 7) ^ srow) * 8;
#pragma unroll
      for (int c = 0; c < 4; ++c) {
        int p = wave * 4 + c;
        gl_lds16(A + (size_t)(m0 + p * 8 + srow) * K + k0 + scol, &As[p * 512]);
        gl_lds16(BT + (size_t)(n0 + p * 8 + srow) * K + k0 + scol, &Bs[p * 512]);
      }
    }
    __syncthreads();
#pragma unroll
    for (int kk = 0; kk < BK / 32; ++kk) {
      bf16x8 af[4], bff[4];
      if constexpr (BK == 32) {
#pragma unroll
        for (int i = 0; i < 4; ++i)
          af[i] = *(const bf16x8*)&As[(wr * 64 + i * 16 + lanem) * 32 + quad * 8];
#pragma unroll
        for (int j = 0; j < 4; ++j)
          bff[j] = *(const bf16x8*)&Bs[(wc * 64 + j * 16 + lanem) * 32 + quad * 8];
      } else {
        const int kp = ((kk * 4 + quad) ^ (lanem & 7)) << 3;
#pragma unroll
        for (int i = 0; i < 4; ++i)
          af[i] = *(const bf16x8*)&As[(wr * 64 + i * 16 + lanem) * 64 + kp];
#pragma unroll
        for (int j = 0; j < 4; ++j)
          bff[j] = *(const bf16x8*)&Bs[(wc * 64 + j * 16 + lanem) * 64 + kp];
      }
#pragma unroll
      for (int i = 0; i < 4; ++i)
#pragma unroll
        for (int j = 0; j < 4; ++j)
          acc[i][j] = mfma16(af[i], bff[j], acc[i][j]);
    }
  }
#pragma unroll
  for (int i = 0; i < 4; ++i)
#pragma unroll
    for (int j = 0; j < 4; ++j) {
      const int row0 = m0 + wr * 64 + i * 16 + quad * 4;
      const int col = n0 + wc * 64 + j * 16 + lanem;
      if constexpr (MODE == 2) {
        if (col >= 2048) {  // V half: transposed store, pack r=0..3
          int cc = col - 2048, hh = cc >> 7, dd = cc & 127;
          int bb = row0 >> 11, ll = row0 & 2047;
          ushort4 pk;
          pk.x = f2bf(acc[i][j][0]);
          pk.y = f2bf(acc[i][j][1]);
          pk.z = f2bf(acc[i][j][2]);
          pk.w = f2bf(acc[i][j][3]);
          *(ushort4*)&C2[((size_t)(bb * 16 + hh) * 128 + dd) * 2048 + ll] = pk;
          continue;
        }
      }
#pragma unroll
      for (int r = 0; r < 4; ++r) {
        float v = acc[i][j][r] * scale;
        if constexpr (MODE == 0)
          ((float*)C)[(size_t)(row0 + r) * ldc + col] = v;
        else if constexpr (MODE == 1)
          ((u16*)C)[(size_t)(row0 + r) * ldc + col] = f2bf(v);
        else
          ((u16*)C)[(size_t)(row0 + r) * 2048 + col] = f2bf(v);
      }
    }
}

// ---------------- causal flash attention, v8: 8-wave shared-KV ----------------
// 512-thread blocks: 8 waves share one K/V stage over 256 q-rows (macro-tile
// mq = 0..7, rows [256mq, 256mq+256)). Same per-wave math as verified v6
// (in-register softmax via permuted-K staging; swapped-operand QK^T).
// Key range split into 2 contiguous chunks of 2mq+2 tiles; 512 blocks total,
// size-paired (class c pairs 16-2c with 2c+2 tiles, sum 18) heavy-first.
// Chunks write NORMALIZED bf16 o-partials + f32 l; k_ared2 merges by
// l-weights (exact: (o0 l0 + o1 l1)/(l0+l1)). Rows fully masked in a chunk
// have l==0 -> store 0 (guarded); partner chunk always has l>0.
// Occupancy: LDS 68KB/block -> 2 blocks/CU = 16 waves/CU (4/SIMD), 2x v6.
__global__ __launch_bounds__(512, 4) void k_attn8(const u16* __restrict__ qg,
                                                  const u16* __restrict__ kg,
                                                  const u16* __restrict__ vtg,
                                                  u16* __restrict__ OPb,
                                                  float* __restrict__ LP) {
  __shared__ __align__(16) u16 Ks[2][64 * 128];   // [row][d] swizzled, permuted keys
  __shared__ __align__(16) u16 VTs[2][144 * 64];  // [d][key] swizzled; 128..143 ones
  const int bid = blockIdx.x;
  const int mq = (bid < 256) ? (7 - (bid >> 6)) : ((bid - 256) >> 6);
  const int uu0 = bid & 63;
  const int ck = uu0 & 1;
  const int uu = uu0 >> 1;
  const int bh = (uu & 7) * 4 + (uu >> 3);  // XCD-grouped heads
  const int b = bh >> 4, h = bh & 15;
  const int ntile = 4 * mq + 4, half = 2 * mq + 2;
  const int ts = ck ? half : 0;
  const int te = ck ? ntile : half;
  const int qb = mq * 256;

  const int tid = threadIdx.x, w = tid >> 6, lane = tid & 63;
  const int lanem = lane & 15, quad = lane >> 4;

  // K staging: 2 gl_lds16/wave; LDS row rho = w*8 + j*4 + kr holds global key
  // lambda(rho) = 32*(rho>>5) + 8*((rho>>2)&3) + 4*((rho>>4)&1) + (rho&3)
  const int kr = lane >> 4, kc = lane & 15;
  const u16* kbp[2];
  int kro[2];
#pragma unroll
  for (int j = 0; j < 2; ++j) {
    const int rho = w * 8 + j * 4 + kr;
    const int key = 32 * (rho >> 5) + 8 * ((rho >> 2) & 3) +
                    4 * ((rho >> 4) & 1) + (rho & 3);
    kbp[j] = kg + (size_t)(b * 2048 + key) * 2048 + h * 128 +
             ((kc ^ (rho & 15)) << 3) + (size_t)ts * 64 * 2048;
    kro[j] = rho * 128;
  }
  // V staging: 2 gl_lds16/wave; rows d = w*16 + j*8 + vr
  const int vr = lane >> 3, vc = lane & 7;
  const u16* vbp[2];
  int vro[2];
#pragma unroll
  for (int j = 0; j < 2; ++j) {
    const int row = w * 16 + j * 8 + vr;
    vbp[j] = vtg + (size_t)(bh * 128 + row) * 2048 + ((vc ^ vr) << 3) +
             (size_t)ts * 64;
    vro[j] = row * 64;
  }

  // Q fragments: 2 subtiles of 16 rows (rows qb + w*32 + g*16 + lanem)
  bf16x8 qf[2][4];
#pragma unroll
  for (int g = 0; g < 2; ++g) {
    const u16* qp = qg +
                    (size_t)(b * 2048 + qb + w * 32 + g * 16 + lanem) * 2304 +
                    h * 128 + quad * 8;
#pragma unroll
    for (int c = 0; c < 4; ++c) qf[g][c] = *(const bf16x8*)(qp + c * 32);
  }
  f32x4 o[2][9] = {};

  // hoisted LDS read offsets
  int kpc[4], vposc[2];
#pragma unroll
  for (int c = 0; c < 4; ++c) kpc[c] = ((c * 4 + quad) ^ lanem) << 3;
#pragma unroll
  for (int kk = 0; kk < 2; ++kk)
    vposc[kk] = ((kk * 4 + quad) ^ (lanem & 7)) << 3;

  // prefetch tile ts into buffer 0; advance pointers
#pragma unroll
  for (int j = 0; j < 2; ++j) gl_lds16(kbp[j], &Ks[0][kro[j]]);
#pragma unroll
  for (int j = 0; j < 2; ++j) gl_lds16(vbp[j], &VTs[0][vro[j]]);
#pragma unroll
  for (int j = 0; j < 2; ++j) { kbp[j] += 64 * 2048; vbp[j] += 64; }
  // ones rows (d=128..143) in both V^T buffers — never re-staged
  {
    const ushort4 ones4{0x3f80u, 0x3f80u, 0x3f80u, 0x3f80u};
    const int bufi = tid >> 8, off = (tid & 255) * 4;
    *(ushort4*)&VTs[bufi][128 * 64 + off] = ones4;
  }

  for (int t = ts; t < te; ++t) {
    __syncthreads();
    if (t + 1 < te) {
      const int nb = (t + 1 - ts) & 1;
#pragma unroll
      for (int j = 0; j < 2; ++j) gl_lds16(kbp[j], &Ks[nb][kro[j]]);
#pragma unroll
      for (int j = 0; j < 2; ++j) gl_lds16(vbp[j], &VTs[nb][vro[j]]);
#pragma unroll
      for (int j = 0; j < 2; ++j) { kbp[j] += 64 * 2048; vbp[j] += 64; }
    }
    const int buf = (t - ts) & 1;
    const u16* ksb = &Ks[buf][lanem * 128];
    const u16* vsb = &VTs[buf][lanem * 64];
    // S^T: swapped operands; lane holds q = lanem, key = lambda(ss,4*quad+r)
    f32x4 s[2][4] = {};
#pragma unroll
    for (int c = 0; c < 4; ++c) {
      const u16* ka = ksb + kpc[c];
#pragma unroll
      for (int ss = 0; ss < 4; ++ss) {
        bf16x8 kf = *(const bf16x8*)(ka + ss * 2048);
        s[0][ss] = mfma16(kf, qf[0][c], s[0][ss]);
        s[1][ss] = mfma16(kf, qf[1][c], s[1][ss]);
      }
    }
    if (t >= ntile - 4) {  // diagonal region: key > row -> -inf (permuted keys)
      const int krel = t * 64 - qb;
#pragma unroll
      for (int g = 0; g < 2; ++g) {
        const int qrow = w * 32 + g * 16 + lanem;
#pragma unroll
        for (int ss = 0; ss < 4; ++ss) {
          const int kb0 = krel + ((ss & 2) << 4) + ((ss & 1) << 2) + (quad << 3);
#pragma unroll
          for (int r = 0; r < 4; ++r)
            if (kb0 + r > qrow) s[g][ss][r] = -1e30f;
        }
      }
    }
    // P = exp2(s), assembled in-register into PV A-fragments:
    // pf[g][f] element j = exp2(s[g][2f + (j>>2)][j&3])
    bf16x8 pf[2][2];
#pragma unroll
    for (int g = 0; g < 2; ++g)
#pragma unroll
      for (int f = 0; f < 2; ++f) {
        u32x4 pw;
        pw.x = pk2bf(EXP2(s[g][2 * f][0]), EXP2(s[g][2 * f][1]));
        pw.y = pk2bf(EXP2(s[g][2 * f][2]), EXP2(s[g][2 * f][3]));
        pw.z = pk2bf(EXP2(s[g][2 * f + 1][0]), EXP2(s[g][2 * f + 1][1]));
        pw.w = pk2bf(EXP2(s[g][2 * f + 1][2]), EXP2(s[g][2 * f + 1][3]));
        pf[g][f] = __builtin_bit_cast(bf16x8, pw);
      }
    // PV: V-frag feeds both subtiles
#pragma unroll
    for (int dc = 0; dc < 9; ++dc) {
      const u16* va = vsb + dc * 1024;
      bf16x8 vf0 = *(const bf16x8*)(va + vposc[0]);
      bf16x8 vf1 = *(const bf16x8*)(va + vposc[1]);
      o[0][dc] = mfma16(pf[0][0], vf0, o[0][dc]);
      o[0][dc] = mfma16(pf[0][1], vf1, o[0][dc]);
      o[1][dc] = mfma16(pf[1][0], vf0, o[1][dc]);
      o[1][dc] = mfma16(pf[1][1], vf1, o[1][dc]);
    }
  }
  // epilogue: normalized bf16 partial + l (0-guarded for fully-masked rows)
  const int slot = (mq * 32 + bh) * 2 + ck;
  u16* opb = OPb + (size_t)slot * 32768;
#pragma unroll
  for (int g = 0; g < 2; ++g)
#pragma unroll
    for (int r = 0; r < 4; ++r) {
      const int row = w * 32 + g * 16 + quad * 4 + r;
      const float l = o[g][8][r];
      const float inv = (l > 0.f) ? (1.f / l) : 0.f;
#pragma unroll
      for (int dc = 0; dc < 8; ++dc)
        opb[row * 128 + dc * 16 + lanem] = f2bf(o[g][dc][r] * inv);
      if (lanem == 0) LP[slot * 256 + row] = l;
    }
}

// ---------------- merge 2 normalized partials by l-weights -> bf16 ----------
__global__ __launch_bounds__(256) void k_ared2(const u16* __restrict__ OPb,
                                               const float* __restrict__ LP,
                                               u16* __restrict__ ao) {
  __shared__ float2 wgt[256];
  const int sp = blockIdx.x;  // mq*32 + bh
  const int mq = sp >> 5, bh = sp & 31;
  const int b = bh >> 4, h = bh & 15;
  const int tid = threadIdx.x;
  const int s0 = sp * 2, s1 = sp * 2 + 1;
  {
    const float l0 = LP[s0 * 256 + tid];
    const float l1 = LP[s1 * 256 + tid];
    const float inv = 1.f / (l0 + l1);
    wgt[tid] = float2{l0 * inv, l1 * inv};
  }
  __syncthreads();
  const ushort4* p0 = (const ushort4*)(OPb + (size_t)s0 * 32768);
  const ushort4* p1 = (const ushort4*)(OPb + (size_t)s1 * 32768);
  u16* abase = ao + (size_t)(b * 2048 + mq * 256) * 2048 + h * 128;
#pragma unroll 4
  for (int k = 0; k < 32; ++k) {
    const int idx = k * 256 + tid;  // ushort4 units over 256x128
    const int row = idx >> 5, d4 = (idx & 31) * 4;
    const ushort4 a4 = p0[idx];
    const ushort4 b4 = p1[idx];
    const float2 wv = wgt[row];
    ushort4 o4;
    o4.x = f2bf(bf2f(a4.x) * wv.x + bf2f(b4.x) * wv.y);
    o4.y = f2bf(bf2f(a4.y) * wv.x + bf2f(b4.y) * wv.y);
    o4.z = f2bf(bf2f(a4.z) * wv.x + bf2f(b4.z) * wv.y);
    o4.w = f2bf(bf2f(a4.w) * wv.x + bf2f(b4.w) * wv.y);
    *(ushort4*)(abase + (size_t)row * 2048 + d4) = o4;
  }
}

// ---------------- fallback: v6 4-wave attention (if ws too small) ----------
__global__ __launch_bounds__(256) void k_attn(const u16* __restrict__ qg,
                                              const u16* __restrict__ kg,
                                              const u16* __restrict__ vtg,
                                              u16* __restrict__ ao) {
  __shared__ __align__(16) u16 Ks[2][64 * 128];
  __shared__ __align__(16) u16 VTs[2][144 * 64];
  const int bid = blockIdx.x;
  const int p = bid >> 5, u = bid & 31;
  const int qt = (bid < 256) ? (15 - p) : (p - 8);
  const int bh = (u & 7) * 4 + (u >> 3);
  const int b = bh >> 4, h = bh & 15;
  const int tid = threadIdx.x, w = tid >> 6, lane = tid & 63;
  const int lanem = lane & 15, quad = lane >> 4;
  const int qb = qt * 128, nt = 2 * qt + 2;
  const int kr = lane >> 4, kc = lane & 15;
  const u16* kbp[4];
#pragma unroll
  for (int j = 0; j < 4; ++j) {
    int key = ((w >> 1) << 5) + (j << 3) + ((w & 1) << 2) + kr;
    kbp[j] = kg + (size_t)(b * 2048 + key) * 2048 + h * 128 +
             ((kc ^ (j * 4 + kr)) << 3);
  }
  const int vr = lane >> 3, vc = lane & 7;
  const u16* vbp[4];
#pragma unroll
  for (int j = 0; j < 4; ++j) {
    int row = w * 32 + j * 8 + vr;
    vbp[j] = vtg + (size_t)(bh * 128 + row) * 2048 + ((vc ^ vr) << 3);
  }
  bf16x8 qf[2][4];
#pragma unroll
  for (int g = 0; g < 2; ++g) {
    const u16* qp = qg +
                    (size_t)(b * 2048 + qb + w * 32 + g * 16 + lanem) * 2304 +
                    h * 128 + quad * 8;
#pragma unroll
    for (int c = 0; c < 4; ++c) qf[g][c] = *(const bf16x8*)(qp + c * 32);
  }
  f32x4 o[2][9] = {};
  int kpc[4], vposc[2];
#pragma unroll
  for (int c = 0; c < 4; ++c) kpc[c] = ((c * 4 + quad) ^ lanem) << 3;
#pragma unroll
  for (int kk = 0; kk < 2; ++kk)
    vposc[kk] = ((kk * 4 + quad) ^ (lanem & 7)) << 3;
#pragma unroll
  for (int j = 0; j < 4; ++j) gl_lds16(kbp[j], &Ks[0][(w * 16 + j * 4) * 128]);
#pragma unroll
  for (int j = 0; j < 4; ++j) gl_lds16(vbp[j], &VTs[0][(w * 32 + j * 8) * 64]);
#pragma unroll
  for (int j = 0; j < 4; ++j) { kbp[j] += 64 * 2048; vbp[j] += 64; }
  {
    const ushort4 ones4{0x3f80u, 0x3f80u, 0x3f80u, 0x3f80u};
    for (int i = tid; i < 512; i += 256) {
      int bufi = i >> 8, off = (i & 255) * 4;
      *(ushort4*)&VTs[bufi][128 * 64 + off] = ones4;
    }
  }
  for (int t = 0; t < nt; ++t) {
    __syncthreads();
    if (t + 1 < nt) {
      int nb = (t + 1) & 1;
#pragma unroll
      for (int j = 0; j < 4; ++j)
        gl_lds16(kbp[j], &Ks[nb][(w * 16 + j * 4) * 128]);
#pragma unroll
      for (int j = 0; j < 4; ++j)
        gl_lds16(vbp[j], &VTs[nb][(w * 32 + j * 8) * 64]);
#pragma unroll
      for (int j = 0; j < 4; ++j) { kbp[j] += 64 * 2048; vbp[j] += 64; }
    }
    const int buf = t & 1;
    const u16* ksb = &Ks[buf][lanem * 128];
    const u16* vsb = &VTs[buf][lanem * 64];
    f32x4 s[2][4] = {};
#pragma unroll
    for (int c = 0; c < 4; ++c) {
      const u16* ka = ksb + kpc[c];
#pragma unroll
      for (int ss = 0; ss < 4; ++ss) {
        bf16x8 kf = *(const bf16x8*)(ka + ss * 2048);
        s[0][ss] = mfma16(kf, qf[0][c], s[0][ss]);
        s[1][ss] = mfma16(kf, qf[1][c], s[1][ss]);
      }
    }
    if (t >= nt - 2) {
      const int krel = t * 64 - qb;
#pragma unroll
      for (int g = 0; g < 2; ++g) {
        const int qrow = w * 32 + g * 16 + lanem;
#pragma unroll
        for (int ss = 0; ss < 4; ++ss) {
          const int kb0 = krel + ((ss & 2) << 4) + ((ss & 1) << 2) + (quad << 3);
#pragma unroll
          for (int r = 0; r < 4; ++r)
            if (kb0 + r > qrow) s[g][ss][r] = -1e30f;
        }
      }
    }
    bf16x8 pf[2][2];
#pragma unroll
    for (int g = 0; g < 2; ++g)
#pragma unroll
      for (int f = 0; f < 2; ++f) {
        u32x4 pw;
        pw.x = pk2bf(EXP2(s[g][2 * f][0]), EXP2(s[g][2 * f][1]));
        pw.y = pk2bf(EXP2(s[g][2 * f][2]), EXP2(s[g][2 * f][3]));
        pw.z = pk2bf(EXP2(s[g][2 * f + 1][0]), EXP2(s[g][2 * f + 1][1]));
        pw.w = pk2bf(EXP2(s[g][2 * f + 1][2]), EXP2(s[g][2 * f + 1][3]));
        pf[g][f] = __builtin_bit_cast(bf16x8, pw);
      }
#pragma unroll
    for (int dc = 0; dc < 9; ++dc) {
      const u16* va = vsb + dc * 1024;
      bf16x8 vf0 = *(const bf16x8*)(va + vposc[0]);
      bf16x8 vf1 = *(const bf16x8*)(va + vposc[1]);
      o[0][dc] = mfma16(pf[0][0], vf0, o[0][dc]);
      o[0][dc] = mfma16(pf[0][1], vf1, o[0][dc]);
      o[1][dc] = mfma16(pf[1][0], vf0, o[1][dc]);
      o[1][dc] = mfma16(pf[1][1], vf1, o[1][dc]);
    }
  }
#pragma unroll
  for (int g = 0; g < 2; ++g)
#pragma unroll
    for (int r = 0; r < 4; ++r) {
      const float inv = 1.f / o[g][8][r];
      u16* op = ao +
                (size_t)(b * 2048 + qb + w * 32 + g * 16 + quad * 4 + r) * 2048 +
                h * 128;
#pragma unroll
      for (int dc = 0; dc < 8; ++dc)
        op[dc * 16 + lanem] = f2bf(o[g][dc][r] * inv);
    }
}

extern "C" void kernel_launch(void* const* d_in, const int* in_sizes, int n_in,
                              void* d_out, int out_size, void* d_ws, size_t ws_size,
                              hipStream_t stream) {
  const float* x    = (const float*)d_in[0];
  const float* Wq   = (const float*)d_in[1];
  const float* Wkvd = (const float*)d_in[2];
  const float* wn   = (const float*)d_in[3];
  const float* Wkvu = (const float*)d_in[4];
  const float* Wo   = (const float*)d_in[5];
  float* out = (float*)d_out;

  char* w0 = (char*)d_ws;
  u16* xbf   = (u16*)(w0);               // 16 MB; reused as aobf after q GEMM
  u16* qc    = (u16*)(w0 + 16777216);    // 4096x2304 bf16 (q | c)
  u16* WqkdT = (u16*)(w0 + 35651584);    // 2304x2048 bf16; latbf reuse
  u16* WoT   = (u16*)(w0 + 45088768);
  u16* WkvuT = (u16*)(w0 + 53477376);
  u16* kbf   = (u16*)(w0 + 55574528);    // 4096x2048 bf16 (K half)
  u16* vtbf  = (u16*)(w0 + 72351744);    // V^T per head, ends at 89128960
  u16* latbf = WqkdT;
  u16* aobf  = xbf;

  // split-K partial buffers (past previous high-water mark; <= R3's usage)
  const size_t PBOFF = 89128960;
  const size_t OPSZ  = 512ull * 256 * 128 * 2;  // 33.55 MB bf16 normalized o
  const size_t LPSZ  = 512ull * 256 * 4;        // 0.5 MB f32 l
  const bool do_split = ws_size >= PBOFF + OPSZ + LPSZ;
  u16* OPb  = (u16*)(w0 + PBOFF);
  float* LP = (float*)(w0 + PBOFF + OPSZ);

  const float sc2 = 0.08838834764831845f * 1.4426950408889634f;

  k_prep<<<17920, 256, 0, stream>>>(x, Wq, Wkvd, Wkvu, Wo, xbf, WqkdT, WkvuT, WoT);
  k_gemm<64, 1><<<dim3(32, 18), 256, 0, stream>>>(xbf, WqkdT, qc, nullptr, 2048,
                                                  2304, sc2);
  k_rmsn<<<1024, 256, 0, stream>>>(qc, wn, latbf);
  k_gemm<64, 2><<<dim3(32, 32), 256, 0, stream>>>(latbf, WkvuT, kbf, vtbf, 256,
                                                  0, 1.0f);
  if (do_split) {
    k_attn8<<<512, 512, 0, stream>>>(qc, kbf, vtbf, OPb, LP);
    k_ared2<<<256, 256, 0, stream>>>(OPb, LP, aobf);
  } else {
    k_attn<<<512, 256, 0, stream>>>(qc, kbf, vtbf, aobf);
  }
  k_gemm<64, 0><<<dim3(32, 16), 256, 0, stream>>>(aobf, WoT, out, nullptr, 2048,
                                                  2048, 1.0f);
}

// Round 5
// 286.048 us; speedup vs baseline: 1.3817x; 1.3817x over previous
//
#include <hip/hip_runtime.h>
#include <cstdint>
#include <cstddef>

typedef unsigned short u16;
typedef __bf16 bf16x8 __attribute__((ext_vector_type(8)));
typedef __bf16 bf16x2 __attribute__((ext_vector_type(2)));
typedef float f32x4 __attribute__((ext_vector_type(4)));
typedef uint32_t u32x4 __attribute__((ext_vector_type(4)));

__device__ inline u16 f2bf(float f) {
  uint32_t u = __builtin_bit_cast(uint32_t, f);
  u += 0x7fffu + ((u >> 16) & 1u);
  return (u16)(u >> 16);
}
__device__ inline float bf2f(u16 u) {
  return __builtin_bit_cast(float, (uint32_t)u << 16);
}

#if defined(__has_builtin)
#if __has_builtin(__builtin_amdgcn_cvt_pk_bf16_f32)
#define HAVE_PK_BF16 1
#endif
#if __has_builtin(__builtin_amdgcn_exp2f)
#define EXP2(x) __builtin_amdgcn_exp2f(x)
#endif
#endif
#ifndef EXP2
#define EXP2(x) exp2f(x)
#endif

__device__ inline uint32_t pk2bf(float a, float b) {
#ifdef HAVE_PK_BF16
  bf16x2 v = __builtin_amdgcn_cvt_pk_bf16_f32(a, b);
  return __builtin_bit_cast(uint32_t, v);
#else
  return (uint32_t)f2bf(a) | ((uint32_t)f2bf(b) << 16);
#endif
}

__device__ inline f32x4 mfma16(bf16x8 a, bf16x8 b, f32x4 c) {
  return __builtin_amdgcn_mfma_f32_16x16x32_bf16(a, b, c, 0, 0, 0);
}

__device__ inline void gl_lds16(const u16* g, u16* l) {
  __builtin_amdgcn_global_load_lds(
      (const __attribute__((address_space(1))) uint32_t*)g,
      (__attribute__((address_space(3))) uint32_t*)l, 16, 0, 0);
}

// ---------------- all input conversions in one launch ----------------
__device__ void tcvt_dev(const float* __restrict__ in, u16* __restrict__ out,
                         int R, int C, int bx, int by, float (*t)[33], int tid) {
  int cb = bx * 32, rb = by * 32;
  int x = tid & 31, y = tid >> 5;
#pragma unroll
  for (int k = 0; k < 4; ++k)
    t[y + k * 8][x] = in[(size_t)(rb + y + k * 8) * C + cb + x];
  __syncthreads();
#pragma unroll
  for (int k = 0; k < 4; ++k)
    out[(size_t)(cb + y + k * 8) * R + rb + x] = f2bf(t[x][y + k * 8]);
}

__global__ __launch_bounds__(256) void k_prep(
    const float* __restrict__ x, const float* __restrict__ Wq,
    const float* __restrict__ Wkvd, const float* __restrict__ Wkvu,
    const float* __restrict__ Wo, u16* __restrict__ xbf,
    u16* __restrict__ WqkdT, u16* __restrict__ WkvuT, u16* __restrict__ WoT) {
  __shared__ float t[32][33];
  int bid = blockIdx.x, tid = threadIdx.x;
  if (bid < 8192) {
    int i = bid * 256 + tid;
    const float4 v = ((const float4*)x)[i];
    ushort4 o;
    o.x = f2bf(v.x); o.y = f2bf(v.y); o.z = f2bf(v.z); o.w = f2bf(v.w);
    ((ushort4*)xbf)[i] = o;
  } else if (bid < 12288) {
    int q = bid - 8192;
    tcvt_dev(Wq, WqkdT, 2048, 2048, q & 63, q >> 6, t, tid);
  } else if (bid < 12800) {
    int q = bid - 12288;
    tcvt_dev(Wkvd, WqkdT + 2048 * 2048, 2048, 256, q & 7, q >> 3, t, tid);
  } else if (bid < 13824) {
    int q = bid - 12800;
    tcvt_dev(Wkvu, WkvuT, 256, 4096, q & 127, q >> 7, t, tid);
  } else {
    int q = bid - 13824;
    tcvt_dev(Wo, WoT, 2048, 2048, q & 63, q >> 6, t, tid);
  }
}

// ---------------- RMSNorm rows of 256 bf16 (scale-invariant) -> bf16 ----------
__global__ __launch_bounds__(256) void k_rmsn(const u16* __restrict__ qc,
                                              const float* __restrict__ w,
                                              u16* __restrict__ out) {
  int row = blockIdx.x * 4 + (threadIdx.x >> 6);
  int lane = threadIdx.x & 63;
  const ushort4 u = *(const ushort4*)(qc + (size_t)row * 2304 + 2048 + lane * 4);
  float4 v;
  v.x = bf2f(u.x); v.y = bf2f(u.y); v.z = bf2f(u.z); v.w = bf2f(u.w);
  float ss = v.x * v.x + v.y * v.y + v.z * v.z + v.w * v.w;
#pragma unroll
  for (int off = 1; off < 64; off <<= 1) ss += __shfl_xor(ss, off);
  float r = rsqrtf(ss * (1.f / 256.f) + 1e-6f);
  const float4 wv = ((const float4*)w)[lane];
  ushort4 o;
  o.x = f2bf(v.x * r * wv.x);
  o.y = f2bf(v.y * r * wv.y);
  o.z = f2bf(v.z * r * wv.z);
  o.w = f2bf(v.w * r * wv.w);
  *(ushort4*)(out + (size_t)row * 256 + lane * 4) = o;
}

// ---------------- GEMM: A[M,K] @ BT[N,K] -> C[M,N] ----------------
// MODE 0: fp32 out. MODE 1: bf16 out, scaled. MODE 2: kv split (K->C, V->C2^T).
template <int BK, int MODE>
__global__ __launch_bounds__(256) void k_gemm(const u16* __restrict__ A,
                                              const u16* __restrict__ BT,
                                              void* __restrict__ C,
                                              u16* __restrict__ C2, int K,
                                              int ldc, float scale) {
  __shared__ __align__(16) u16 As[128 * BK];
  __shared__ __align__(16) u16 Bs[128 * BK];
  const int tid = threadIdx.x, wave = tid >> 6, lane = tid & 63;
  const int lanem = lane & 15, quad = lane >> 4;
  const int m0 = blockIdx.x * 128, n0 = blockIdx.y * 128;
  const int wr = wave >> 1, wc = wave & 1;
  f32x4 acc[4][4] = {};
  for (int k0 = 0; k0 < K; k0 += BK) {
    __syncthreads();
    if constexpr (BK == 32) {
      const int srow = lane >> 2, scol = (lane & 3) * 8;
#pragma unroll
      for (int c = 0; c < 2; ++c) {
        int p = wave * 2 + c;
        gl_lds16(A + (size_t)(m0 + p * 16 + srow) * K + k0 + scol, &As[p * 512]);
        gl_lds16(BT + (size_t)(n0 + p * 16 + srow) * K + k0 + scol, &Bs[p * 512]);
      }
    } else {
      const int srow = lane >> 3;
      const int scol = ((lane & 7) ^ srow) * 8;
#pragma unroll
      for (int c = 0; c < 4; ++c) {
        int p = wave * 4 + c;
        gl_lds16(A + (size_t)(m0 + p * 8 + srow) * K + k0 + scol, &As[p * 512]);
        gl_lds16(BT + (size_t)(n0 + p * 8 + srow) * K + k0 + scol, &Bs[p * 512]);
      }
    }
    __syncthreads();
#pragma unroll
    for (int kk = 0; kk < BK / 32; ++kk) {
      bf16x8 af[4], bff[4];
      if constexpr (BK == 32) {
#pragma unroll
        for (int i = 0; i < 4; ++i)
          af[i] = *(const bf16x8*)&As[(wr * 64 + i * 16 + lanem) * 32 + quad * 8];
#pragma unroll
        for (int j = 0; j < 4; ++j)
          bff[j] = *(const bf16x8*)&Bs[(wc * 64 + j * 16 + lanem) * 32 + quad * 8];
      } else {
        const int kp = ((kk * 4 + quad) ^ (lanem & 7)) << 3;
#pragma unroll
        for (int i = 0; i < 4; ++i)
          af[i] = *(const bf16x8*)&As[(wr * 64 + i * 16 + lanem) * 64 + kp];
#pragma unroll
        for (int j = 0; j < 4; ++j)
          bff[j] = *(const bf16x8*)&Bs[(wc * 64 + j * 16 + lanem) * 64 + kp];
      }
#pragma unroll
      for (int i = 0; i < 4; ++i)
#pragma unroll
        for (int j = 0; j < 4; ++j)
          acc[i][j] = mfma16(af[i], bff[j], acc[i][j]);
    }
  }
#pragma unroll
  for (int i = 0; i < 4; ++i)
#pragma unroll
    for (int j = 0; j < 4; ++j) {
      const int row0 = m0 + wr * 64 + i * 16 + quad * 4;
      const int col = n0 + wc * 64 + j * 16 + lanem;
      if constexpr (MODE == 2) {
        if (col >= 2048) {  // V half: transposed store, pack r=0..3
          int cc = col - 2048, hh = cc >> 7, dd = cc & 127;
          int bb = row0 >> 11, ll = row0 & 2047;
          ushort4 pk;
          pk.x = f2bf(acc[i][j][0]);
          pk.y = f2bf(acc[i][j][1]);
          pk.z = f2bf(acc[i][j][2]);
          pk.w = f2bf(acc[i][j][3]);
          *(ushort4*)&C2[((size_t)(bb * 16 + hh) * 128 + dd) * 2048 + ll] = pk;
          continue;
        }
      }
#pragma unroll
      for (int r = 0; r < 4; ++r) {
        float v = acc[i][j][r] * scale;
        if constexpr (MODE == 0)
          ((float*)C)[(size_t)(row0 + r) * ldc + col] = v;
        else if constexpr (MODE == 1)
          ((u16*)C)[(size_t)(row0 + r) * ldc + col] = f2bf(v);
        else
          ((u16*)C)[(size_t)(row0 + r) * 2048 + col] = f2bf(v);
      }
    }
}

// ---------------- causal flash attention, v9: 8-wave, 16 rows/wave ----------
// Same verified v6 math (in-register softmax via permuted-K staging,
// swapped-operand QK^T), but 8 waves of 16 q-rows each share one K/V stage
// (q-tile 128 rows, LDS 68KB -> 2 blocks/CU = 16 waves/CU = 4/SIMD, 2x v6's
// latency hiding). Per-thread state ~105 regs (o 36 + qf 16 + s 16 + pf 8 +
// addr) fits the 128-reg/16-wave tier; launch_bounds(512,3) caps regalloc at
// ~170 so a miss degrades occupancy instead of spilling (R4 lesson: the
// (512,4)=128-unified cap forced 64 arch VGPR -> 546 MB scratch traffic).
// K LDS row rho holds global key lambda(rho)=32(rho>>5)+8((rho>>2)&3)
// +4((rho>>4)&1)+(rho&3); staging dests are wave-uniform (rho = w*8+j*4+kr,
// uniform part w*8+j*4, lane fills +kr). Grid/pairing identical to v6.
__global__ __launch_bounds__(512, 3) void k_attn16(const u16* __restrict__ qg,
                                                   const u16* __restrict__ kg,
                                                   const u16* __restrict__ vtg,
                                                   u16* __restrict__ ao) {
  __shared__ __align__(16) u16 Ks[2][64 * 128];   // [row][d] swizzled, permuted keys
  __shared__ __align__(16) u16 VTs[2][144 * 64];  // [d][key] swizzled; 128..143 ones
  const int bid = blockIdx.x;
  const int p = bid >> 5, u = bid & 31;
  const int qt = (bid < 256) ? (15 - p) : (p - 8);  // pair sums = 15 per CU
  const int bh = (u & 7) * 4 + (u >> 3);            // XCD-grouped heads
  const int b = bh >> 4, h = bh & 15;
  const int tid = threadIdx.x, w = tid >> 6, lane = tid & 63;
  const int lanem = lane & 15, quad = lane >> 4;
  const int qb = qt * 128, nt = 2 * qt + 2;

  // K staging: per wave 2 calls, rows rho in [w*8+j*4, w*8+j*4+4)
  const int kr = lane >> 4, kc = lane & 15;
  const u16* kbp[2];
#pragma unroll
  for (int j = 0; j < 2; ++j) {
    const int rho = w * 8 + j * 4 + kr;
    const int key = 32 * (rho >> 5) + 8 * ((rho >> 2) & 3) +
                    4 * ((rho >> 4) & 1) + (rho & 3);
    kbp[j] = kg + (size_t)(b * 2048 + key) * 2048 + h * 128 +
             ((kc ^ (rho & 15)) << 3);
  }
  // V staging: per wave 2 calls, rows d in [w*16+j*8, w*16+j*8+8)
  const int vr = lane >> 3, vc = lane & 7;
  const u16* vbp[2];
#pragma unroll
  for (int j = 0; j < 2; ++j) {
    const int row = w * 16 + j * 8 + vr;
    vbp[j] = vtg + (size_t)(bh * 128 + row) * 2048 + ((vc ^ vr) << 3);
  }

  // Q fragments: 16 rows qb + w*16 + lanem
  bf16x8 qf[4];
  {
    const u16* qp = qg + (size_t)(b * 2048 + qb + w * 16 + lanem) * 2304 +
                    h * 128 + quad * 8;
#pragma unroll
    for (int c = 0; c < 4; ++c) qf[c] = *(const bf16x8*)(qp + c * 32);
  }
  f32x4 o[9] = {};

  // hoisted LDS read offsets
  int kpc[4], vposc[2];
#pragma unroll
  for (int c = 0; c < 4; ++c) kpc[c] = ((c * 4 + quad) ^ lanem) << 3;
#pragma unroll
  for (int kk = 0; kk < 2; ++kk)
    vposc[kk] = ((kk * 4 + quad) ^ (lanem & 7)) << 3;

  // prefetch tile 0 into buffer 0; advance pointers to tile 1
#pragma unroll
  for (int j = 0; j < 2; ++j)
    gl_lds16(kbp[j], &Ks[0][(w * 8 + j * 4) * 128]);
#pragma unroll
  for (int j = 0; j < 2; ++j)
    gl_lds16(vbp[j], &VTs[0][(w * 16 + j * 8) * 64]);
#pragma unroll
  for (int j = 0; j < 2; ++j) { kbp[j] += 64 * 2048; vbp[j] += 64; }
  // ones rows (d=128..143) in both V^T buffers — never re-staged
  {
    const ushort4 ones4{0x3f80u, 0x3f80u, 0x3f80u, 0x3f80u};
    const int bufi = tid >> 8, off = (tid & 255) * 4;
    *(ushort4*)&VTs[bufi][128 * 64 + off] = ones4;
  }

  for (int t = 0; t < nt; ++t) {
    __syncthreads();
    if (t + 1 < nt) {
      const int nb = (t + 1) & 1;
#pragma unroll
      for (int j = 0; j < 2; ++j)
        gl_lds16(kbp[j], &Ks[nb][(w * 8 + j * 4) * 128]);
#pragma unroll
      for (int j = 0; j < 2; ++j)
        gl_lds16(vbp[j], &VTs[nb][(w * 16 + j * 8) * 64]);
#pragma unroll
      for (int j = 0; j < 2; ++j) { kbp[j] += 64 * 2048; vbp[j] += 64; }
    }
    const int buf = t & 1;
    const u16* ksb = &Ks[buf][lanem * 128];
    const u16* vsb = &VTs[buf][lanem * 64];
    // S^T: swapped operands; lane holds q = lanem, key = lambda(16ss+4quad+r)
    f32x4 s[4] = {};
#pragma unroll
    for (int c = 0; c < 4; ++c) {
      const u16* ka = ksb + kpc[c];
#pragma unroll
      for (int ss = 0; ss < 4; ++ss) {
        bf16x8 kf = *(const bf16x8*)(ka + ss * 2048);
        s[ss] = mfma16(kf, qf[c], s[ss]);
      }
    }
    if (t >= nt - 2) {  // diagonal region: key > row -> -inf (permuted keys)
      const int krel = t * 64 - qb;
      const int qrow = w * 16 + lanem;
#pragma unroll
      for (int ss = 0; ss < 4; ++ss) {
        const int kb0 = krel + ((ss & 2) << 4) + ((ss & 1) << 2) + (quad << 3);
#pragma unroll
        for (int r = 0; r < 4; ++r)
          if (kb0 + r > qrow) s[ss][r] = -1e30f;
      }
    }
    // P = exp2(s), assembled in-register into PV A-fragments:
    // pf[f] element j = exp2(s[2f + (j>>2)][j&3])
    bf16x8 pf[2];
#pragma unroll
    for (int f = 0; f < 2; ++f) {
      u32x4 pw;
      pw.x = pk2bf(EXP2(s[2 * f][0]), EXP2(s[2 * f][1]));
      pw.y = pk2bf(EXP2(s[2 * f][2]), EXP2(s[2 * f][3]));
      pw.z = pk2bf(EXP2(s[2 * f + 1][0]), EXP2(s[2 * f + 1][1]));
      pw.w = pk2bf(EXP2(s[2 * f + 1][2]), EXP2(s[2 * f + 1][3]));
      pf[f] = __builtin_bit_cast(bf16x8, pw);
    }
    // PV
#pragma unroll
    for (int dc = 0; dc < 9; ++dc) {
      const u16* va = vsb + dc * 1024;
      bf16x8 vf0 = *(const bf16x8*)(va + vposc[0]);
      bf16x8 vf1 = *(const bf16x8*)(va + vposc[1]);
      o[dc] = mfma16(pf[0], vf0, o[dc]);
      o[dc] = mfma16(pf[1], vf1, o[dc]);
    }
  }
  // epilogue: normalize by l (ones-tile) and store
#pragma unroll
  for (int r = 0; r < 4; ++r) {
    const float inv = 1.f / o[8][r];
    u16* op = ao +
              (size_t)(b * 2048 + qb + w * 16 + quad * 4 + r) * 2048 + h * 128;
#pragma unroll
    for (int dc = 0; dc < 8; ++dc)
      op[dc * 16 + lanem] = f2bf(o[dc][r] * inv);
  }
}

extern "C" void kernel_launch(void* const* d_in, const int* in_sizes, int n_in,
                              void* d_out, int out_size, void* d_ws, size_t ws_size,
                              hipStream_t stream) {
  const float* x    = (const float*)d_in[0];
  const float* Wq   = (const float*)d_in[1];
  const float* Wkvd = (const float*)d_in[2];
  const float* wn   = (const float*)d_in[3];
  const float* Wkvu = (const float*)d_in[4];
  const float* Wo   = (const float*)d_in[5];
  float* out = (float*)d_out;

  char* w0 = (char*)d_ws;
  u16* xbf   = (u16*)(w0);               // 16 MB; reused as aobf after q GEMM
  u16* qc    = (u16*)(w0 + 16777216);    // 4096x2304 bf16 (q | c)
  u16* WqkdT = (u16*)(w0 + 35651584);    // 2304x2048 bf16; latbf reuse
  u16* WoT   = (u16*)(w0 + 45088768);
  u16* WkvuT = (u16*)(w0 + 53477376);
  u16* kbf   = (u16*)(w0 + 55574528);    // 4096x2048 bf16 (K half)
  u16* vtbf  = (u16*)(w0 + 72351744);    // V^T per head, ends at 89128960
  u16* latbf = WqkdT;
  u16* aobf  = xbf;

  const float sc2 = 0.08838834764831845f * 1.4426950408889634f;

  k_prep<<<17920, 256, 0, stream>>>(x, Wq, Wkvd, Wkvu, Wo, xbf, WqkdT, WkvuT, WoT);
  k_gemm<64, 1><<<dim3(32, 18), 256, 0, stream>>>(xbf, WqkdT, qc, nullptr, 2048,
                                                  2304, sc2);
  k_rmsn<<<1024, 256, 0, stream>>>(qc, wn, latbf);
  k_gemm<64, 2><<<dim3(32, 32), 256, 0, stream>>>(latbf, WkvuT, kbf, vtbf, 256,
                                                  0, 1.0f);
  k_attn16<<<512, 512, 0, stream>>>(qc, kbf, vtbf, aobf);
  k_gemm<64, 0><<<dim3(32, 16), 256, 0, stream>>>(aobf, WoT, out, nullptr, 2048,
                                                  2048, 1.0f);
}